// Round 7
// baseline (3082.435 us; speedup 1.0000x reference)
//
#include <hip/hip_runtime.h>
#include <cstdint>

typedef unsigned short u16;
typedef unsigned long long u64;
typedef __attribute__((ext_vector_type(8))) short s8v;   // 8 x bf16 (4 VGPR)
typedef __attribute__((ext_vector_type(4))) float f4v;   // MFMA 16x16 acc

#define NBLK 128
#define TSEQ 200
#define PIPE_W 8
#define HSLOT (256 * 512)

__device__ __forceinline__ u16 f2bf(float f) {
  uint32_t u = __float_as_uint(f);
  u += 0x7fffu + ((u >> 16) & 1u);
  return (u16)(u >> 16);
}
__device__ __forceinline__ float bf2f(u16 h) {
  return __uint_as_float(((uint32_t)h) << 16);
}
__device__ __forceinline__ float sigf(float x) { return 1.f / (1.f + __expf(-x)); }
__device__ __forceinline__ float tanhfast(float x) { return 2.f / (1.f + __expf(-2.f * x)) - 1.f; }

// asm loads so ALL vmem in the phase is under counted-vmcnt control.
// ld_c: coherent (LLC) for H state; ld_nc: plain cached for static X.
// NOTE: offset: must precede sc0/sc1 on gfx950.
__device__ __forceinline__ void ld_c(s8v& d, const u16* p, int ofs) {
  asm volatile("global_load_dwordx4 %0, %1, off offset:%2 sc0 sc1"
               : "=v"(d) : "v"(p), "n"(ofs));
}
__device__ __forceinline__ void ld_nc(s8v& d, const u16* p, int ofs) {
  asm volatile("global_load_dwordx4 %0, %1, off offset:%2"
               : "=v"(d) : "v"(p), "n"(ofs));
}
__device__ __forceinline__ void vmwait(int n) {
  asm volatile("s_waitcnt vmcnt(%0)" :: "n"(n) : "memory");
}
__device__ __forceinline__ void cstore(u16* p, u16 v) {
  asm volatile("global_store_short %0, %1, off sc0 sc1" :: "v"(p), "v"((uint32_t)v) : "memory");
}

// ---------------- precompute kernels ----------------

__global__ void zero_ws(uint32_t* p, int n) {
  int i = blockIdx.x * 256 + threadIdx.x;
  if (i < n) p[i] = 0u;
}

// X[t][b(256)][e(128)] bf16, zero-padded rows b>=250 and cols e>=100
__global__ void gather_x(const int* __restrict__ tokens, const float* __restrict__ emb,
                         u16* __restrict__ X) {
  int idx = blockIdx.x * 256 + threadIdx.x;
  if (idx >= TSEQ * 256 * 16) return;
  int e0 = (idx & 15) * 8;
  int b  = (idx >> 4) & 255;
  int t  = idx >> 12;
  u16 v[8];
  if (b < 250) {
    int tok = tokens[b * TSEQ + t];
    const float* er = emb + (size_t)tok * 100;
#pragma unroll
    for (int j = 0; j < 8; ++j) {
      int e = e0 + j;
      v[j] = (e < 100) ? f2bf(er[e]) : (u16)0;
    }
  } else {
#pragma unroll
    for (int j = 0; j < 8; ++j) v[j] = 0;
  }
  *(s8v*)&X[(size_t)idx * 8] = *(const s8v*)v;
}

// out[ub(32)][ks(nks)][col(64)][kw(32)] bf16 with 16B-slot XOR swizzle within each
// 64B kw-row: slot' = slot ^ ((col>>1)&3). col = g*16+j -> orig column g*512+ub*16+j.
// k = ks*32+kw : k<split -> A (zero for k>=arows), else Bm[k-split]
__global__ void pack_w(const float* __restrict__ A, const float* __restrict__ Bm,
                       u16* __restrict__ out, int nks, int split, int arows) {
  int idx = blockIdx.x * 256 + threadIdx.x;
  int total = 32 * nks * 256;
  if (idx >= total) return;
  int kw0 = (idx & 3) * 8;
  int col = (idx >> 2) & 63;
  int rest = idx >> 8;
  int ks = rest % nks;
  int ub = rest / nks;
  int g = col >> 4, j = col & 15;
  int oc = g * 512 + ub * 16 + j;
  u16 v[8];
#pragma unroll
  for (int w = 0; w < 8; ++w) {
    int k = ks * 32 + kw0 + w;
    float f;
    if (k < split) f = (k < arows) ? A[(size_t)k * 2048 + oc] : 0.f;
    else           f = Bm[(size_t)(k - split) * 2048 + oc];
    v[w] = f2bf(f);
  }
  int kw0s = kw0 ^ ((((col >> 1) & 3)) << 3);   // bank-conflict swizzle
  size_t dst = (((size_t)(ub * nks + ks) * 64 + col) * 32) + kw0s;
  *(s8v*)&out[dst] = *(const s8v*)v;
}

// ---------------- decoupled per-group sync ----------------

// Wave 0 polls 64 compact flags per group (one 4B load/lane); others park at the sync.
__device__ __forceinline__ void wait2(const unsigned* fA, int tA, const unsigned* fB, int tB) {
  if (threadIdx.x < 64) {
    const int l = threadIdx.x;
    const bool needA = tA > 0, needB = tB > 0;
    if (needA || needB) {
      unsigned a, b;
      do {
        a = needA ? __hip_atomic_load((unsigned*)&fA[l], __ATOMIC_RELAXED, __HIP_MEMORY_SCOPE_AGENT) : 0u;
        b = needB ? __hip_atomic_load((unsigned*)&fB[l], __ATOMIC_RELAXED, __HIP_MEMORY_SCOPE_AGENT) : 0u;
      } while (!__all((!needA || (int)a >= tA) && (!needB || (int)b >= tB)));
    }
  }
  __syncthreads();
}

// Drain this wave's sc1 stores, block-sync, publish progress.
__device__ __forceinline__ void signal(unsigned* f, int idx, unsigned val) {
  asm volatile("s_waitcnt vmcnt(0)" ::: "memory");
  __syncthreads();
  if (threadIdx.x == 0)
    __hip_atomic_store(&f[idx], val, __ATOMIC_RELAXED, __HIP_MEMORY_SCOPE_AGENT);
}

// Sync-only probe: identical flag protocol, zero work. Time inferred as
// headline_dur - lstm_main_dur from rocprof.
__global__ void __launch_bounds__(512, 2) sync_probe(unsigned* fA, unsigned* fB) {
  const int blk = blockIdx.x;
  const bool Lh = blk >= 64;
  const int idx = blk & 63;
  for (int t = 0; t < TSEQ; ++t) {
    if (!Lh) wait2(fA, t, fB, t - 3);
    else     wait2(fA, t + 1, fB, t);
    signal(Lh ? fB : fA, idx, (unsigned)(t + 1));
  }
}

// ---------------- persistent LSTM kernel ----------------

// Windowed software pipeline over NK k-steps, 2 m-tiles. Steps i<NX load from X
// (plain), others from H (sc1 coherent). Counted vmcnt keeps W steps in flight.
template <int NK, int NX>
__device__ __forceinline__ void gemmpipe(const u16* ax0, const u16* ax1,
                                         const u16* ah0, const u16* ah1,
                                         const u16* ldsW, int ldsb, f4v acc[2][4]) {
  s8v a[2][NK];
  constexpr int W = (PIPE_W < NK) ? PIPE_W : NK;
#pragma unroll
  for (int i = 0; i < W; ++i) {
    if (i < NX) { ld_nc(a[0][i], ax0, i * 64); ld_nc(a[1][i], ax1, i * 64); }
    else        { ld_c(a[0][i], ah0, (i - NX) * 64); ld_c(a[1][i], ah1, (i - NX) * 64); }
  }
#pragma unroll
  for (int i = 0; i < NK; ++i) {
    if (i + W < NK) {
      const int j = i + W;
      if (j < NX) { ld_nc(a[0][j], ax0, j * 64); ld_nc(a[1][j], ax1, j * 64); }
      else        { ld_c(a[0][j], ah0, (j - NX) * 64); ld_c(a[1][j], ah1, (j - NX) * 64); }
    }
    const int rem = NK - 1 - i;
    vmwait(2 * (W < rem ? W : rem));   // step i's 2 loads complete; window stays full
    __builtin_amdgcn_sched_barrier(0); // don't hoist MFMA above the wait (rule 18)
    s8v b[4];
#pragma unroll
    for (int g = 0; g < 4; ++g) b[g] = *(const s8v*)&ldsW[i * 2048 + g * 512 + ldsb];
#pragma unroll
    for (int m = 0; m < 2; ++m)
#pragma unroll
      for (int g = 0; g < 4; ++g)
        acc[m][g] = __builtin_amdgcn_mfma_f32_16x16x32_bf16(a[m][i], b[g], acc[m][g], 0, 0, 0);
  }
}

__device__ __forceinline__ void epilogue(const f4v acc[4], const float bias[4], float cst[4],
                                         u16* __restrict__ Hout, int drow, int ucol) {
#pragma unroll
  for (int r = 0; r < 4; ++r) {
    float gi = acc[0][r] + bias[0];
    float gf = acc[1][r] + bias[1];
    float gc = acc[2][r] + bias[2];
    float go = acc[3][r] + bias[3];
    float cn = sigf(gf) * cst[r] + sigf(gi) * tanhfast(gc);
    cst[r] = cn;
    cstore(&Hout[(size_t)(drow + r) * 512 + ucol], f2bf(sigf(go) * tanhfast(cn)));
  }
}

__global__ void __launch_bounds__(512, 2)
lstm_main(const float* __restrict__ b0, const float* __restrict__ b1,
          const u16* __restrict__ W0p, const u16* __restrict__ W1p,
          const u16* __restrict__ X, u16* __restrict__ H0,
          u16* __restrict__ H1, unsigned* __restrict__ fL0,
          unsigned* __restrict__ fL1) {
  extern __shared__ u16 lds[];
  const int tid = threadIdx.x;
  const int lane = tid & 63;
  const int w = tid >> 6;                // 0..7
  const int wm = w & 3;                  // M sub-position (32 rows each)
  const int kh = w >> 2;                 // K-half (0 or 1)
  const int blk = blockIdx.x;
  const bool Lh = (blk >= 64);           // layer-1 block?
  const int sub = blk & 63;
  const int ub = sub & 31;               // u-tile (16 units)
  const int mt = sub >> 5;               // M half (128 rows)
  const int NKr = Lh ? 32 : 20;

  // stationary B slice -> LDS (once). layout [ks][col][kw], swizzled slots.
  {
    const u16* src = (Lh ? W1p : W0p) + (size_t)ub * (NKr * 2048);
    const int total = NKr * 2048;
    for (int ofs = tid * 8; ofs < total; ofs += 4096)
      *(s8v*)&lds[ofs] = *(const s8v*)&src[ofs];
  }
  __syncthreads();

  const int colu = lane & 15;                            // frag col = u within tile
  const int kch = (lane >> 4) * 8;                       // A/B k-chunk (elements)
  const int kchs = kch ^ ((((colu >> 1) & 3)) << 3);     // swizzled LDS slot
  const int arow0 = mt * 128 + wm * 32 + colu;           // A row, m-tile 0
  const int drow0 = mt * 128 + wm * 32 + ((lane >> 4) << 2);
  const int ucol = ub * 16 + colu;                       // global unit index
  const int ldsb = colu * 32 + kchs;
  float* rbuf = (float*)(lds + 65536);                   // 16 KB reduce buffer @128KB

  float bias[4];
  {
    const float* bp = Lh ? b1 : b0;
#pragma unroll
    for (int g = 0; g < 4; ++g) bias[g] = bp[g * 512 + ucol];
  }

  float cst[2][4] = {{0.f, 0.f, 0.f, 0.f}, {0.f, 0.f, 0.f, 0.f}};

  for (int t = 0; t < TSEQ; ++t) {
    const int cs = t & 3;                 // slot being written this step
    const int ps = (t + 3) & 3;           // slot of step t-1
    // ---- sync: own-group data + other-group ring safety ----
    if (!Lh) wait2(fL0, t, fL1, t - 3);
    else     wait2(fL0, t + 1, fL1, t);

    f4v acc[2][4] = {};
    if (!Lh) {
      if (kh == 0) {  // K 0..320: X (4 steps, plain) + H0 cols 0..192 (6 steps, sc1)
        const u16* ax0 = X + ((size_t)t * 256 + arow0) * 128 + kch;
        const u16* ah0 = H0 + (size_t)ps * HSLOT + (size_t)arow0 * 512 + kch;
        gemmpipe<10, 4>(ax0, ax0 + 16 * 128, ah0, ah0 + 16 * 512, lds, ldsb, acc);
      } else {        // K 320..640: H0 cols 192..512 (10 steps)
        const u16* ah = H0 + (size_t)ps * HSLOT + (size_t)arow0 * 512 + 192 + kch;
        gemmpipe<10, 0>(ah, ah, ah, ah + 16 * 512, lds + 10 * 2048, ldsb, acc);
      }
    } else {
      if (kh == 0) {  // K 0..512: h0[t] (k1 part)
        const u16* ah = H0 + (size_t)cs * HSLOT + (size_t)arow0 * 512 + kch;
        gemmpipe<16, 0>(ah, ah, ah, ah + 16 * 512, lds, ldsb, acc);
      } else {        // K 512..1024: h1[t-1] (r1 part)
        const u16* ah = H1 + (size_t)ps * HSLOT + (size_t)arow0 * 512 + kch;
        gemmpipe<16, 0>(ah, ah, ah, ah + 16 * 512, lds + 16 * 2048, ldsb, acc);
      }
    }
    // reduce K-halves: kh=1 waves ship partials to kh=0 via 16KB LDS, 2 rounds.
#pragma unroll
    for (int r = 0; r < 2; ++r) {
      __syncthreads();
      if (kh == 1) {
#pragma unroll
        for (int m = 0; m < 2; ++m)
#pragma unroll
          for (int gg = 0; gg < 2; ++gg) {
            int q = m * 2 + gg;
            *(f4v*)&rbuf[(((size_t)q * 4 + wm) * 64 + lane) * 4] = acc[m][2 * r + gg];
          }
      }
      __syncthreads();
      if (kh == 0) {
#pragma unroll
        for (int m = 0; m < 2; ++m)
#pragma unroll
          for (int gg = 0; gg < 2; ++gg) {
            int q = m * 2 + gg;
            acc[m][2 * r + gg] += *(const f4v*)&rbuf[(((size_t)q * 4 + wm) * 64 + lane) * 4];
          }
      }
    }
    if (kh == 0) {
      u16* Hout = (Lh ? H1 : H0) + (size_t)cs * HSLOT;
      epilogue(acc[0], bias, cst[0], Hout, drow0, ucol);
      epilogue(acc[1], bias, cst[1], Hout, drow0 + 16, ucol);
    }
    if (!Lh) signal(fL0, sub, (unsigned)(t + 1));
    else     signal(fL1, sub, (unsigned)(t + 1));
  }
}

// ---------------- final dense (affine collapse) + sigmoid ----------------

__global__ void dense_out(const u16* __restrict__ H1f, const float* __restrict__ wd1,
                          const float* __restrict__ bd1, const float* __restrict__ wd2,
                          const float* __restrict__ bd2, float* __restrict__ out) {
  __shared__ float wv[512];
  __shared__ float beff;
  const int t = threadIdx.x;  // 512 threads
  {
    float s = 0.f;
#pragma unroll 4
    for (int j = 0; j < 32; ++j) s += wd1[t * 32 + j] * wd2[j];
    wv[t] = s;
  }
  if (t == 0) {
    float sb = 0.f;
    for (int j = 0; j < 32; ++j) sb += bd1[j] * wd2[j];
    beff = sb + bd2[0];
  }
  __syncthreads();
  if (t < 250) {
    const u16* hr = H1f + (size_t)t * 512;
    float acc = 0.f;
    for (int u = 0; u < 512; u += 8) {
      s8v hv = *(const s8v*)&hr[u];
#pragma unroll
      for (int j = 0; j < 8; ++j) acc += bf2f((u16)hv[j]) * wv[u + j];
    }
    out[t] = sigf(acc + beff);
  }
}

// ---------------- host ----------------

extern "C" void kernel_launch(void* const* d_in, const int* in_sizes, int n_in,
                              void* d_out, int out_size, void* d_ws, size_t ws_size,
                              hipStream_t stream) {
  const int*   tokens = (const int*)  d_in[0];
  const float* emb    = (const float*)d_in[1];
  const float* k0     = (const float*)d_in[2];
  const float* r0     = (const float*)d_in[3];
  const float* b0     = (const float*)d_in[4];
  const float* k1     = (const float*)d_in[5];
  const float* r1     = (const float*)d_in[6];
  const float* b1     = (const float*)d_in[7];
  const float* wd1    = (const float*)d_in[8];
  const float* bd1    = (const float*)d_in[9];
  const float* wd2    = (const float*)d_in[10];
  const float* bd2    = (const float*)d_in[11];
  float* out = (float*)d_out;

  char* ws = (char*)d_ws;
  // layout: [0,256) fL0 ; [512,768) fL1 ; [1024,1280) probeA ; [1536,1792) probeB ;
  // H0 ring 4x256KB @8192 ; H1 ring 4x256KB ; X 12.5MB ; W0p 2.5MB ; W1p 4MB
  unsigned* fL0 = (unsigned*)ws;
  unsigned* fL1 = (unsigned*)(ws + 512);
  unsigned* pA  = (unsigned*)(ws + 1024);
  unsigned* pB  = (unsigned*)(ws + 1536);
  u16* H0  = (u16*)(ws + 8192);
  u16* H1  = (u16*)(ws + 8192 + 1048576);
  u16* X   = (u16*)(ws + 8192 + 2097152);
  u16* W0p = (u16*)(ws + 8192 + 2097152 + 13107200);
  u16* W1p = (u16*)(ws + 8192 + 2097152 + 13107200 + 2621440);

  zero_ws<<<2056, 256, 0, stream>>>((uint32_t*)ws, 526336);    // flags + H0/H1 rings
  gather_x<<<3200, 256, 0, stream>>>(tokens, emb, X);
  pack_w<<<640,  256, 0, stream>>>(k0, r0, W0p, 20, 128, 100); // layer0: K=128(pad)+512
  pack_w<<<1024, 256, 0, stream>>>(k1, r1, W1p, 32, 512, 512); // layer1: K=512+512

  // sync-floor probe (diagnostic; time = headline - lstm_main)
  void* pargs[] = {(void*)&pA, (void*)&pB};
  (void)hipLaunchCooperativeKernel(reinterpret_cast<void*>(sync_probe),
                                   dim3(NBLK), dim3(512), pargs, 0, stream);

  hipFuncSetAttribute(reinterpret_cast<const void*>(lstm_main),
                      hipFuncAttributeMaxDynamicSharedMemorySize, 147456);
  void* args[] = {(void*)&b0, (void*)&b1, (void*)&W0p, (void*)&W1p,
                  (void*)&X,  (void*)&H0, (void*)&H1, (void*)&fL0, (void*)&fL1};
  (void)hipLaunchCooperativeKernel(reinterpret_cast<void*>(lstm_main),
                                   dim3(NBLK), dim3(512), args, 147456, stream);

  dense_out<<<1, 512, 0, stream>>>(H1 + (size_t)3 * HSLOT, wd1, bd1, wd2, bd2, out);
}

// Round 8
// 2097.330 us; speedup vs baseline: 1.4697x; 1.4697x over previous
//
#include <hip/hip_runtime.h>
#include <cstdint>

typedef unsigned short u16;
typedef unsigned long long u64;
typedef __attribute__((ext_vector_type(8))) short s8v;   // 8 x bf16 (4 VGPR)
typedef __attribute__((ext_vector_type(4))) float f4v;   // MFMA 16x16 acc

#define NBLK 256
#define TSEQ 200
#define PIPE_W 8
#define HSLOT (256 * 512)

__device__ __forceinline__ u16 f2bf(float f) {
  uint32_t u = __float_as_uint(f);
  u += 0x7fffu + ((u >> 16) & 1u);
  return (u16)(u >> 16);
}
__device__ __forceinline__ float bf2f(u16 h) {
  return __uint_as_float(((uint32_t)h) << 16);
}
__device__ __forceinline__ float sigf(float x) { return 1.f / (1.f + __expf(-x)); }
__device__ __forceinline__ float tanhfast(float x) { return 2.f / (1.f + __expf(-2.f * x)) - 1.f; }

// NOTE: offset: must precede sc0/sc1 on gfx950.
__device__ __forceinline__ void ld_c(s8v& d, const u16* p, int ofs) {
  asm volatile("global_load_dwordx4 %0, %1, off offset:%2 sc0 sc1"
               : "=v"(d) : "v"(p), "n"(ofs));
}
__device__ __forceinline__ void ld_nc(s8v& d, const u16* p, int ofs) {
  asm volatile("global_load_dwordx4 %0, %1, off offset:%2"
               : "=v"(d) : "v"(p), "n"(ofs));
}
__device__ __forceinline__ void vmwait(int n) {
  asm volatile("s_waitcnt vmcnt(%0)" :: "n"(n) : "memory");
}
__device__ __forceinline__ void cstore(u16* p, u16 v) {
  asm volatile("global_store_short %0, %1, off sc0 sc1" :: "v"(p), "v"((uint32_t)v) : "memory");
}

// ---------------- precompute kernels ----------------

__global__ void zero_ws(uint32_t* p, int n) {
  int i = blockIdx.x * 256 + threadIdx.x;
  if (i < n) p[i] = 0u;
}

// X[t][b(256)][e(128)] bf16, zero-padded rows b>=250 and cols e>=100
__global__ void gather_x(const int* __restrict__ tokens, const float* __restrict__ emb,
                         u16* __restrict__ X) {
  int idx = blockIdx.x * 256 + threadIdx.x;
  if (idx >= TSEQ * 256 * 16) return;
  int e0 = (idx & 15) * 8;
  int b  = (idx >> 4) & 255;
  int t  = idx >> 12;
  u16 v[8];
  if (b < 250) {
    int tok = tokens[b * TSEQ + t];
    const float* er = emb + (size_t)tok * 100;
#pragma unroll
    for (int j = 0; j < 8; ++j) {
      int e = e0 + j;
      v[j] = (e < 100) ? f2bf(er[e]) : (u16)0;
    }
  } else {
#pragma unroll
    for (int j = 0; j < 8; ++j) v[j] = 0;
  }
  *(s8v*)&X[(size_t)idx * 8] = *(const s8v*)v;
}

// out[ub(32)][ks(nks)][col(64)][kw(32)] bf16 with 16B-slot XOR swizzle within each
// 64B kw-row: slot' = slot ^ ((col>>1)&3). col = g*16+j -> orig column g*512+ub*16+j.
// k = ks*32+kw : k<split -> A (zero for k>=arows), else Bm[k-split]
__global__ void pack_w(const float* __restrict__ A, const float* __restrict__ Bm,
                       u16* __restrict__ out, int nks, int split, int arows) {
  int idx = blockIdx.x * 256 + threadIdx.x;
  int total = 32 * nks * 256;
  if (idx >= total) return;
  int kw0 = (idx & 3) * 8;
  int col = (idx >> 2) & 63;
  int rest = idx >> 8;
  int ks = rest % nks;
  int ub = rest / nks;
  int g = col >> 4, j = col & 15;
  int oc = g * 512 + ub * 16 + j;
  u16 v[8];
#pragma unroll
  for (int w = 0; w < 8; ++w) {
    int k = ks * 32 + kw0 + w;
    float f;
    if (k < split) f = (k < arows) ? A[(size_t)k * 2048 + oc] : 0.f;
    else           f = Bm[(size_t)(k - split) * 2048 + oc];
    v[w] = f2bf(f);
  }
  int kw0s = kw0 ^ ((((col >> 1) & 3)) << 3);   // bank-conflict swizzle
  size_t dst = (((size_t)(ub * nks + ks) * 64 + col) * 32) + kw0s;
  *(s8v*)&out[dst] = *(const s8v*)v;
}

// ---------------- wave-autonomous pipeline ----------------

// NK k-steps, one 16-row m-tile per wave. Load source: j<S1 -> p0 plain (X);
// S1<=j<S2 -> p1 coherent; j>=S2 -> p2 coherent. Counted vmcnt window; ds_reads
// hoisted above the wait so MFMA_i overlaps ds_read_{i+1} within each SB region.
template <int NK, int S1, int S2>
__device__ __forceinline__ void pipew(const u16* p0, const u16* p1, const u16* p2,
                                      const u16* ldsW, int ldsb, f4v acc[4]) {
  s8v a[NK];
  constexpr int W = (PIPE_W < NK) ? PIPE_W : NK;
#pragma unroll
  for (int j = 0; j < W; ++j) {
    if (j < S1)      ld_nc(a[j], p0, j * 64);
    else if (j < S2) ld_c(a[j], p1, (j - S1) * 64);
    else             ld_c(a[j], p2, (j - S2) * 64);
  }
#pragma unroll
  for (int i = 0; i < NK; ++i) {
    const int j = i + W;
    if (j < NK) {
      if (j < S1)      ld_nc(a[j], p0, j * 64);
      else if (j < S2) ld_c(a[j], p1, (j - S1) * 64);
      else             ld_c(a[j], p2, (j - S2) * 64);
    }
    s8v b0 = *(const s8v*)&ldsW[i * 2048 + 0 * 512 + ldsb];
    s8v b1 = *(const s8v*)&ldsW[i * 2048 + 1 * 512 + ldsb];
    s8v b2 = *(const s8v*)&ldsW[i * 2048 + 2 * 512 + ldsb];
    s8v b3 = *(const s8v*)&ldsW[i * 2048 + 3 * 512 + ldsb];
    const int rem = NK - 1 - i;
    vmwait(W < rem ? W : rem);          // a[i] complete; window stays full
    __builtin_amdgcn_sched_barrier(0);  // rule 18: keep MFMA below the wait
    acc[0] = __builtin_amdgcn_mfma_f32_16x16x32_bf16(a[i], b0, acc[0], 0, 0, 0);
    acc[1] = __builtin_amdgcn_mfma_f32_16x16x32_bf16(a[i], b1, acc[1], 0, 0, 0);
    acc[2] = __builtin_amdgcn_mfma_f32_16x16x32_bf16(a[i], b2, acc[2], 0, 0, 0);
    acc[3] = __builtin_amdgcn_mfma_f32_16x16x32_bf16(a[i], b3, acc[3], 0, 0, 0);
  }
}

// ---------------- persistent LSTM kernel (no __syncthreads in main loop) ----------------

__global__ void __launch_bounds__(256, 1)
lstm_main(const float* __restrict__ b0, const float* __restrict__ b1,
          const u16* __restrict__ W0p, const u16* __restrict__ W1p,
          const u16* __restrict__ X, u16* __restrict__ H0,
          u16* __restrict__ H1, unsigned* __restrict__ fL0,
          unsigned* __restrict__ fL1) {
  extern __shared__ u16 lds[];
  const int tid = threadIdx.x;
  const int lane = tid & 63;
  const int w = tid >> 6;              // wave 0..3 -> 16-row slice
  const int blk = blockIdx.x;
  const bool Lh = (blk >= 128);        // layer-1?
  const int sub = blk & 127;
  const int ub = sub & 31;             // u-tile (16 units)
  const int mt = sub >> 5;             // 0..3 (64-row band)
  const int NKr = Lh ? 32 : 20;

  // stationary B slice -> LDS (once). layout [ks][col][kw], swizzled slots.
  {
    const u16* src = (Lh ? W1p : W0p) + (size_t)ub * (NKr * 2048);
    const int total = NKr * 2048;
    for (int ofs = tid * 8; ofs < total; ofs += 2048)
      *(s8v*)&lds[ofs] = *(const s8v*)&src[ofs];
  }
  __syncthreads();   // weights ready (only sync outside the loop)

  const int colu = lane & 15;
  const int kch = (lane >> 4) * 8;
  const int kchs = kch ^ ((((colu >> 1) & 3)) << 3);
  const int arow = mt * 64 + w * 16 + colu;
  const int drow = mt * 64 + w * 16 + ((lane >> 4) << 2);
  const int ucol = ub * 16 + colu;
  const int ldsb = colu * 32 + kchs;

  // per-wave flag lattice: f[mt][wave][ub]
  unsigned* gL0 = fL0 + (mt * 4 + w) * 32;
  unsigned* gL1 = fL1 + (mt * 4 + w) * 32;
  unsigned* pollp = (lane < 32 ? gL0 : gL1) + (lane & 31);
  const int thrOfs = Lh ? (lane < 32 ? 1 : 0)       // L1: h0[t] ready ; h1[t-1] ready
                        : (lane < 32 ? 0 : -3);     // L0: h0[t-1] ready ; ring safety
  unsigned* sigp = (Lh ? gL1 : gL0) + ub;

  float bias[4];
  {
    const float* bp = Lh ? b1 : b0;
#pragma unroll
    for (int g = 0; g < 4; ++g) bias[g] = bp[g * 512 + ucol];
  }

  float cst[4] = {0.f, 0.f, 0.f, 0.f};

  for (int t = 0; t < TSEQ; ++t) {
    const int cs = t & 3;              // slot written this step
    const int ps = (t + 3) & 3;        // slot of step t-1
    // ---- per-wave poll (both conditions in one 64-lane ballot) ----
    {
      const int thr = t + thrOfs;
      unsigned v;
      do {
        v = __hip_atomic_load(pollp, __ATOMIC_RELAXED, __HIP_MEMORY_SCOPE_AGENT);
      } while (!__all((int)v >= thr));
    }
    f4v acc[4] = {};
    if (!Lh) {
      const u16* ax = X + ((size_t)t * 256 + arow) * 128 + kch;
      const u16* ah = H0 + (size_t)ps * HSLOT + (size_t)arow * 512 + kch;
      pipew<20, 4, 20>(ax, ah, ah, lds, ldsb, acc);
    } else {
      const u16* ak = H0 + (size_t)cs * HSLOT + (size_t)arow * 512 + kch;
      const u16* ar = H1 + (size_t)ps * HSLOT + (size_t)arow * 512 + kch;
      pipew<32, 0, 16>(ak, ak, ar, lds, ldsb, acc);
    }
    // ---- epilogue: gates -> c,h ; coherent 2B stores ----
    u16* Hout = (Lh ? H1 : H0) + (size_t)cs * HSLOT;
#pragma unroll
    for (int r = 0; r < 4; ++r) {
      float gi = acc[0][r] + bias[0];
      float gf = acc[1][r] + bias[1];
      float gc = acc[2][r] + bias[2];
      float go = acc[3][r] + bias[3];
      float cn = sigf(gf) * cst[r] + sigf(gi) * tanhfast(gc);
      cst[r] = cn;
      cstore(&Hout[(size_t)(drow + r) * 512 + ucol], f2bf(sigf(go) * tanhfast(cn)));
    }
    asm volatile("s_waitcnt vmcnt(0)" ::: "memory");   // h at LLC
    if (lane == 0)
      __hip_atomic_store(sigp, (unsigned)(t + 1), __ATOMIC_RELAXED, __HIP_MEMORY_SCOPE_AGENT);
  }
}

// ---------------- final dense (affine collapse) + sigmoid ----------------

__global__ void dense_out(const u16* __restrict__ H1f, const float* __restrict__ wd1,
                          const float* __restrict__ bd1, const float* __restrict__ wd2,
                          const float* __restrict__ bd2, float* __restrict__ out) {
  __shared__ float wv[512];
  __shared__ float beff;
  const int t = threadIdx.x;  // 512 threads
  {
    float s = 0.f;
#pragma unroll 4
    for (int j = 0; j < 32; ++j) s += wd1[t * 32 + j] * wd2[j];
    wv[t] = s;
  }
  if (t == 0) {
    float sb = 0.f;
    for (int j = 0; j < 32; ++j) sb += bd1[j] * wd2[j];
    beff = sb + bd2[0];
  }
  __syncthreads();
  if (t < 250) {
    const u16* hr = H1f + (size_t)t * 512;
    float acc = 0.f;
    for (int u = 0; u < 512; u += 8) {
      s8v hv = *(const s8v*)&hr[u];
#pragma unroll
      for (int j = 0; j < 8; ++j) acc += bf2f((u16)hv[j]) * wv[u + j];
    }
    out[t] = sigf(acc + beff);
  }
}

// ---------------- host ----------------

extern "C" void kernel_launch(void* const* d_in, const int* in_sizes, int n_in,
                              void* d_out, int out_size, void* d_ws, size_t ws_size,
                              hipStream_t stream) {
  const int*   tokens = (const int*)  d_in[0];
  const float* emb    = (const float*)d_in[1];
  const float* k0     = (const float*)d_in[2];
  const float* r0     = (const float*)d_in[3];
  const float* b0     = (const float*)d_in[4];
  const float* k1     = (const float*)d_in[5];
  const float* r1     = (const float*)d_in[6];
  const float* b1     = (const float*)d_in[7];
  const float* wd1    = (const float*)d_in[8];
  const float* bd1    = (const float*)d_in[9];
  const float* wd2    = (const float*)d_in[10];
  const float* bd2    = (const float*)d_in[11];
  float* out = (float*)d_out;

  char* ws = (char*)d_ws;
  // layout: [0,2048) fL0[mt][w][ub] ; [2048,4096) fL1 ; H0 ring 4x256KB @8192 ;
  //         H1 ring 4x256KB ; X 12.5MB ; W0p 2.5MB ; W1p 4MB
  unsigned* fL0 = (unsigned*)ws;
  unsigned* fL1 = (unsigned*)(ws + 2048);
  u16* H0  = (u16*)(ws + 8192);
  u16* H1  = (u16*)(ws + 8192 + 1048576);
  u16* X   = (u16*)(ws + 8192 + 2097152);
  u16* W0p = (u16*)(ws + 8192 + 2097152 + 13107200);
  u16* W1p = (u16*)(ws + 8192 + 2097152 + 13107200 + 2621440);

  zero_ws<<<2056, 256, 0, stream>>>((uint32_t*)ws, 526336);    // flags + H rings
  gather_x<<<3200, 256, 0, stream>>>(tokens, emb, X);
  pack_w<<<640,  256, 0, stream>>>(k0, r0, W0p, 20, 128, 100); // layer0: K=128(pad)+512
  pack_w<<<1024, 256, 0, stream>>>(k1, r1, W1p, 32, 512, 512); // layer1: K=512+512

  hipFuncSetAttribute(reinterpret_cast<const void*>(lstm_main),
                      hipFuncAttributeMaxDynamicSharedMemorySize, 131072);
  void* args[] = {(void*)&b0, (void*)&b1, (void*)&W0p, (void*)&W1p,
                  (void*)&X,  (void*)&H0, (void*)&H1, (void*)&fL0, (void*)&fL1};
  (void)hipLaunchCooperativeKernel(reinterpret_cast<void*>(lstm_main),
                                   dim3(NBLK), dim3(256), args, 131072, stream);

  dense_out<<<1, 512, 0, stream>>>(H1 + (size_t)3 * HSLOT, wd1, bd1, wd2, bd2, out);
}

// Round 9
// 1879.727 us; speedup vs baseline: 1.6398x; 1.1158x over previous
//
#include <hip/hip_runtime.h>
#include <cstdint>

typedef unsigned short u16;
typedef __attribute__((ext_vector_type(8))) short s8v;    // 8 x bf16
typedef __attribute__((ext_vector_type(4))) float f4v;
typedef __attribute__((ext_vector_type(16))) float f16v;  // 32x32 MFMA acc

#define TSEQ 200
#define HSLOT (256 * 512)

__device__ __forceinline__ u16 f2bf(float f) {
  uint32_t u = __float_as_uint(f);
  u += 0x7fffu + ((u >> 16) & 1u);
  return (u16)(u >> 16);
}
__device__ __forceinline__ float bf2f(u16 h) {
  return __uint_as_float(((uint32_t)h) << 16);
}
__device__ __forceinline__ float sigf(float x) { return 1.f / (1.f + __expf(-x)); }
__device__ __forceinline__ float tanhfast(float x) { return 2.f / (1.f + __expf(-2.f * x)) - 1.f; }

// coherent (LLC) / plain loads; offset: must precede sc0/sc1 on gfx950
__device__ __forceinline__ void ld_c(s8v& d, const u16* p, int ofs) {
  asm volatile("global_load_dwordx4 %0, %1, off offset:%2 sc0 sc1"
               : "=v"(d) : "v"(p), "n"(ofs));
}
__device__ __forceinline__ void ld_nc(s8v& d, const u16* p, int ofs) {
  asm volatile("global_load_dwordx4 %0, %1, off offset:%2"
               : "=v"(d) : "v"(p), "n"(ofs));
}
__device__ __forceinline__ void vmwait(int n) {
  asm volatile("s_waitcnt vmcnt(%0)" :: "n"(n) : "memory");
}
__device__ __forceinline__ void cstore(u16* p, u16 v) {
  asm volatile("global_store_short %0, %1, off sc0 sc1" :: "v"(p), "v"((uint32_t)v) : "memory");
}

// ---------------- precompute ----------------

__global__ void zero_ws(uint32_t* p, int n) {
  int i = blockIdx.x * 256 + threadIdx.x;
  if (i < n) p[i] = 0u;
}

// X[t][b(256)][e(128)] bf16, zero-padded b>=250, e>=100
__global__ void gather_x(const int* __restrict__ tokens, const float* __restrict__ emb,
                         u16* __restrict__ X) {
  int idx = blockIdx.x * 256 + threadIdx.x;
  if (idx >= TSEQ * 256 * 16) return;
  int e0 = (idx & 15) * 8;
  int b  = (idx >> 4) & 255;
  int t  = idx >> 12;
  u16 v[8];
  if (b < 250) {
    int tok = tokens[b * TSEQ + t];
    const float* er = emb + (size_t)tok * 100;
#pragma unroll
    for (int j = 0; j < 8; ++j) {
      int e = e0 + j;
      v[j] = (e < 100) ? f2bf(er[e]) : (u16)0;
    }
  } else {
#pragma unroll
    for (int j = 0; j < 8; ++j) v[j] = 0;
  }
  *(s8v*)&X[(size_t)idx * 8] = *(const s8v*)v;
}

// Pack weights for 32x32x16 B-frags, register-resident.
// layout [ub(32)][ks(nk16)][colt(2)][col(32)][kh(2)][e(8)] bf16.
// element k = ks*16+kh*8+e ; gate-col = (colt*2+(col>>4))*512 + ub*16 + (col&15)
__global__ void pack_wB(const float* __restrict__ A, const float* __restrict__ Bm,
                        u16* __restrict__ out, int nk16, int split, int arows) {
  int idx = blockIdx.x * 256 + threadIdx.x;
  int total = 32 * nk16 * 2 * 32 * 2;
  if (idx >= total) return;
  int kh = idx & 1;
  int col = (idx >> 1) & 31;
  int colt = (idx >> 6) & 1;
  int rest = idx >> 7;
  int ks = rest % nk16;
  int ub = rest / nk16;
  int gcol = (colt * 2 + (col >> 4)) * 512 + ub * 16 + (col & 15);
  u16 v[8];
#pragma unroll
  for (int e = 0; e < 8; ++e) {
    int k = ks * 16 + kh * 8 + e;
    float f;
    if (k < split) f = (k < arows) ? A[(size_t)k * 2048 + gcol] : 0.f;
    else           f = Bm[(size_t)(k - split) * 2048 + gcol];
    v[e] = f2bf(f);
  }
  *(s8v*)&out[(size_t)idx * 8] = *(const s8v*)v;
}

// ---------------- per-band wave-cooperative layer body ----------------
// Block = 32 rows (band) x 16 units (ub) x full K, K split over 4 waves.
// B-frags live in registers for all 200 steps. Cross-wave reduce via LDS.
template <bool LH, int NS, int NK16, int NX>
__device__ __forceinline__ void run_layer(int band, int ub, int w, int lane, int tid,
    const u16* __restrict__ Wp, const u16* __restrict__ X,
    u16* __restrict__ H0, u16* __restrict__ H1,
    const float* __restrict__ bp, unsigned* fL0b, unsigned* fL1b, float* rbuf) {
  // ---- persistent B registers: NS k16-slots x 2 col-tiles ----
  s8v B0[NS], B1[NS];
#pragma unroll
  for (int s = 0; s < NS; ++s) {
    const u16* bb = Wp + (size_t)(ub * NK16 + w * NS + s) * 1024
                       + ((lane & 31) * 2 + (lane >> 5)) * 8;
    B0[s] = *(const s8v*)bb;
    B1[s] = *(const s8v*)(bb + 512);
  }
  const int arow = band * 32 + (lane & 31);
  const int kchE = (lane >> 5) * 8;
  const int u0 = (tid * 2) & 15;
  float bias0[4], bias1[4];
#pragma unroll
  for (int g = 0; g < 4; ++g) {
    bias0[g] = bp[g * 512 + ub * 16 + u0];
    bias1[g] = bp[g * 512 + ub * 16 + u0 + 1];
  }
  float c0 = 0.f, c1 = 0.f;
  // ---- per-wave poll target ----
  unsigned* pp; int tofs;
  if (LH) {
    if (w < 2) { pp = fL0b + (lane & 31); tofs = 1; }   // need h0[t]
    else       { pp = fL1b + (lane & 31); tofs = 0; }   // need h1[t-1]
  } else {
    pp = (lane < 32) ? (fL0b + lane) : (fL1b + (lane - 32));
    tofs = (lane < 32) ? 0 : -3;                        // h0[t-1] ; ring safety
  }
  unsigned* sigp = (LH ? fL1b : fL0b) + ub;

  for (int t = 0; t < TSEQ; ++t) {
    const int cs = t & 3, ps = (t + 3) & 3;
    {  // poll (band-local flags)
      const int thr = t + tofs;
      unsigned v;
      do {
        v = __hip_atomic_load(pp, __ATOMIC_RELAXED, __HIP_MEMORY_SCOPE_AGENT);
      } while (!__all((int)v >= thr));
    }
    // ---- A bases for this wave's k-slice ----
    const u16 *pH, *pX;
    if (LH) {
      pH = (w < 2 ? H0 + (size_t)cs * HSLOT : H1 + (size_t)ps * HSLOT)
           + (size_t)arow * 512 + kchE + (w & 1) * 256;
      pX = pH;
    } else if (NX > 0) {  // L0 wave 0: 8 X-slots + 2 h0-slots
      pX = X + (size_t)t * 32768 + arow * 128 + kchE;
      pH = H0 + (size_t)ps * HSLOT + (size_t)arow * 512 + kchE - 128;
    } else {              // L0 waves 1-3: h0 slice
      pH = H0 + (size_t)ps * HSLOT + (size_t)arow * 512 + kchE + (w * 10 - 8) * 16;
      pX = pH;
    }
    // ---- pipelined loads + 32x32x16 MFMA ----
    f16v acc0 = {}, acc1 = {};
    s8v a[NS];
    constexpr int W = NS < 8 ? NS : 8;
#pragma unroll
    for (int s = 0; s < W; ++s) {
      if (s < NX) ld_nc(a[s], pX, s * 32); else ld_c(a[s], pH, s * 32);
    }
#pragma unroll
    for (int s = 0; s < NS; ++s) {
      const int j = s + W;
      if (j < NS) { if (j < NX) ld_nc(a[j], pX, j * 32); else ld_c(a[j], pH, j * 32); }
      const int rem = NS - 1 - s;
      vmwait(rem < W ? rem : W);
      __builtin_amdgcn_sched_barrier(0);  // rule 18
      acc0 = __builtin_amdgcn_mfma_f32_32x32x16_bf16(a[s], B0[s], acc0, 0, 0, 0);
      acc1 = __builtin_amdgcn_mfma_f32_32x32x16_bf16(a[s], B1[s], acc1, 0, 0, 0);
    }
    // ---- raw partials -> LDS [w][colt][q][lane][4] ----
#pragma unroll
    for (int q = 0; q < 4; ++q) {
      f4v v0 = {acc0[4*q], acc0[4*q+1], acc0[4*q+2], acc0[4*q+3]};
      f4v v1 = {acc1[4*q], acc1[4*q+1], acc1[4*q+2], acc1[4*q+3]};
      *(f4v*)&rbuf[(w * 8 + q) * 256 + lane * 4] = v0;
      *(f4v*)&rbuf[(w * 8 + 4 + q) * 256 + lane * 4] = v1;
    }
    __syncthreads();
    // ---- epilogue: 2 cells/thread, sum 4 wave-partials, gates -> c,h ----
    u16* Hout = (LH ? H1 : H0) + (size_t)cs * HSLOT;
    {
      const int cell = tid * 2, row = cell >> 4, u = cell & 15;
      const int hi = (row >> 2) & 1, r = (row & 3) | ((row >> 3) << 2);
      float gs[4];
#pragma unroll
      for (int g = 0; g < 4; ++g) {
        const int dwb = ((g >> 1) * 4 + (r >> 2)) * 256 + (((g & 1) << 4) + u + (hi << 5)) * 4 + (r & 3);
        gs[g] = rbuf[dwb] + rbuf[dwb + 2048] + rbuf[dwb + 4096] + rbuf[dwb + 6144];
      }
      float cn = sigf(gs[1] + bias0[1]) * c0 + sigf(gs[0] + bias0[0]) * tanhfast(gs[2] + bias0[2]);
      c0 = cn;
      cstore(&Hout[(size_t)(band * 32 + row) * 512 + ub * 16 + u],
             f2bf(sigf(gs[3] + bias0[3]) * tanhfast(cn)));
    }
    {
      const int cell = tid * 2 + 1, row = cell >> 4, u = cell & 15;
      const int hi = (row >> 2) & 1, r = (row & 3) | ((row >> 3) << 2);
      float gs[4];
#pragma unroll
      for (int g = 0; g < 4; ++g) {
        const int dwb = ((g >> 1) * 4 + (r >> 2)) * 256 + (((g & 1) << 4) + u + (hi << 5)) * 4 + (r & 3);
        gs[g] = rbuf[dwb] + rbuf[dwb + 2048] + rbuf[dwb + 4096] + rbuf[dwb + 6144];
      }
      float cn = sigf(gs[1] + bias1[1]) * c1 + sigf(gs[0] + bias1[0]) * tanhfast(gs[2] + bias1[2]);
      c1 = cn;
      cstore(&Hout[(size_t)(band * 32 + row) * 512 + ub * 16 + u],
             f2bf(sigf(gs[3] + bias1[3]) * tanhfast(cn)));
    }
    vmwait(0);          // h at LLC
    __syncthreads();    // all threads' stores drained (also LDS WAR guard)
    if (tid == 0)
      __hip_atomic_store(sigp, (unsigned)(t + 1), __ATOMIC_RELAXED, __HIP_MEMORY_SCOPE_AGENT);
  }
}

__global__ void __launch_bounds__(256, 2)
lstm_main(const float* __restrict__ b0, const float* __restrict__ b1,
          const u16* __restrict__ W0p, const u16* __restrict__ W1p,
          const u16* __restrict__ X, u16* __restrict__ H0,
          u16* __restrict__ H1, unsigned* __restrict__ fL0,
          unsigned* __restrict__ fL1) {
  __shared__ float rbuf[8192];   // 32 KB raw-accumulator exchange
  const int tid = threadIdx.x, lane = tid & 63, w = tid >> 6;
  const int blk = blockIdx.x;
  const bool Lh = blk >= 256;
  const int sub = blk & 255, band = sub >> 5, ub = sub & 31;
  unsigned* fL0b = fL0 + band * 32;
  unsigned* fL1b = fL1 + band * 32;
  if (Lh)
    run_layer<true, 16, 64, 0>(band, ub, w, lane, tid, W1p, X, H0, H1, b1, fL0b, fL1b, rbuf);
  else if (w == 0)
    run_layer<false, 10, 40, 8>(band, ub, w, lane, tid, W0p, X, H0, H1, b0, fL0b, fL1b, rbuf);
  else
    run_layer<false, 10, 40, 0>(band, ub, w, lane, tid, W0p, X, H0, H1, b0, fL0b, fL1b, rbuf);
}

// ---------------- final dense (affine collapse) + sigmoid ----------------

__global__ void dense_out(const u16* __restrict__ H1f, const float* __restrict__ wd1,
                          const float* __restrict__ bd1, const float* __restrict__ wd2,
                          const float* __restrict__ bd2, float* __restrict__ out) {
  __shared__ float wv[512];
  __shared__ float beff;
  const int t = threadIdx.x;  // 512 threads
  {
    float s = 0.f;
#pragma unroll 4
    for (int j = 0; j < 32; ++j) s += wd1[t * 32 + j] * wd2[j];
    wv[t] = s;
  }
  if (t == 0) {
    float sb = 0.f;
    for (int j = 0; j < 32; ++j) sb += bd1[j] * wd2[j];
    beff = sb + bd2[0];
  }
  __syncthreads();
  if (t < 250) {
    const u16* hr = H1f + (size_t)t * 512;
    float acc = 0.f;
    for (int u = 0; u < 512; u += 8) {
      s8v hv = *(const s8v*)&hr[u];
#pragma unroll
      for (int j = 0; j < 8; ++j) acc += bf2f((u16)hv[j]) * wv[u + j];
    }
    out[t] = sigf(acc + beff);
  }
}

// ---------------- host ----------------

extern "C" void kernel_launch(void* const* d_in, const int* in_sizes, int n_in,
                              void* d_out, int out_size, void* d_ws, size_t ws_size,
                              hipStream_t stream) {
  const int*   tokens = (const int*)  d_in[0];
  const float* emb    = (const float*)d_in[1];
  const float* k0     = (const float*)d_in[2];
  const float* r0     = (const float*)d_in[3];
  const float* b0     = (const float*)d_in[4];
  const float* k1     = (const float*)d_in[5];
  const float* r1     = (const float*)d_in[6];
  const float* b1     = (const float*)d_in[7];
  const float* wd1    = (const float*)d_in[8];
  const float* bd1    = (const float*)d_in[9];
  const float* wd2    = (const float*)d_in[10];
  const float* bd2    = (const float*)d_in[11];
  float* out = (float*)d_out;

  char* ws = (char*)d_ws;
  // layout: fL0[8][32] @0 ; fL1 @2048 ; H0 ring 4x256KB @8192 ; H1 ring ;
  //         X 12.5MB ; W0p 2.5MB ; W1p 4MB
  unsigned* fL0 = (unsigned*)ws;
  unsigned* fL1 = (unsigned*)(ws + 2048);
  u16* H0  = (u16*)(ws + 8192);
  u16* H1  = (u16*)(ws + 8192 + 1048576);
  u16* X   = (u16*)(ws + 8192 + 2097152);
  u16* W0p = (u16*)(ws + 8192 + 2097152 + 13107200);
  u16* W1p = (u16*)(ws + 8192 + 2097152 + 13107200 + 2621440);

  zero_ws<<<2056, 256, 0, stream>>>((uint32_t*)ws, 526336);      // flags + H rings
  gather_x<<<3200, 256, 0, stream>>>(tokens, emb, X);
  pack_wB<<<640,  256, 0, stream>>>(k0, r0, W0p, 40, 128, 100);  // L0: K=128(pad)+512
  pack_wB<<<1024, 256, 0, stream>>>(k1, r1, W1p, 64, 512, 512);  // L1: K=512+512

  void* args[] = {(void*)&b0, (void*)&b1, (void*)&W0p, (void*)&W1p,
                  (void*)&X,  (void*)&H0, (void*)&H1, (void*)&fL0, (void*)&fL1};
  (void)hipLaunchCooperativeKernel(reinterpret_cast<void*>(lstm_main),
                                   dim3(512), dim3(256), args, 0, stream);

  dense_out<<<1, 512, 0, stream>>>(H1 + (size_t)3 * HSLOT, wd1, bd1, wd2, bd2, out);
}